// Round 1
// baseline (9237.456 us; speedup 1.0000x reference)
//
#include <hip/hip_runtime.h>
#include <hip/hip_bf16.h>

#define N_NODES 10000
#define N_EDGES 70000
#define H 128
#define NLAYERS 15
constexpr float LN_EPS = 1e-5f;

// ---------------- prep kernels ----------------
__global__ void prep_node_attr(const int* __restrict__ node_type,
                               const float* __restrict__ frames,
                               const float* __restrict__ nmean,
                               const float* __restrict__ nstd,
                               float* __restrict__ a16) {
    int i = blockIdx.x * blockDim.x + threadIdx.x;  // over N*16
    if (i >= N_NODES * 16) return;
    int n = i >> 4, k = i & 15;
    float v = 0.f;
    if (k < 11) {
        float raw;
        if (k < 2) raw = frames[n * 2 + k];
        else       raw = (node_type[n] == (k - 2)) ? 1.f : 0.f;
        v = (raw - nmean[k]) / nstd[k];
    }
    a16[i] = v;
}

__global__ void prep_edge_attr(const float* __restrict__ ef, float* __restrict__ a4) {
    int i = blockIdx.x * blockDim.x + threadIdx.x;  // over E*4
    if (i >= N_EDGES * 4) return;
    int e = i >> 2, k = i & 3;
    a4[i] = (k < 3) ? ef[e * 3 + k] : 0.f;
}

__global__ void prep_pad_w(const float* __restrict__ w, float* __restrict__ out,
                           int krows, int kpad) {
    int i = blockIdx.x * blockDim.x + threadIdx.x;  // over kpad*H
    if (i >= kpad * H) return;
    int k = i / H, c = i % H;
    out[i] = (k < krows) ? w[k * H + c] : 0.f;
}

// ---------------- fused GEMM ----------------
// Tile: 64 rows x 128 cols, 256 threads, each thread owns 8 rows x 4 cols.
// AMODE: 0 = plain A [rows][K]; 1 = edge concat (x[snd], x[rcv], e); 2 = node concat (x, agg)
// EPI:   0 = +bias, relu -> store out
//        1 = +bias, LN   -> store out
//        2 = +bias, LN   -> out += v   (node residual)
//        3 = +bias, LN   -> eout += v, atomicAdd agg[rcv[row]] += v
template <int K, int KC, int AMODE, int EPI>
__launch_bounds__(256, 2)
__global__ void gemm_fused(const float* __restrict__ A,
                           const float* __restrict__ X,
                           const float* __restrict__ Ebuf,
                           const float* __restrict__ AGG,
                           const int* __restrict__ snd,
                           const int* __restrict__ rcv,
                           const float* __restrict__ B,
                           const float* __restrict__ bias,
                           const float* __restrict__ lng,
                           const float* __restrict__ lnb,
                           float* __restrict__ out,
                           float* __restrict__ eout,
                           float* __restrict__ agg_out,
                           int nrows) {
    constexpr int TM = 64;
    constexpr int STRIDE = KC + 4;  // keep multiple of 4 words for b128 alignment
    __shared__ float As[TM * STRIDE];
    __shared__ float Bs[KC * H];

    const int tid = threadIdx.x;
    const int tc = tid & 31;   // col group (4 cols)
    const int tr = tid >> 5;   // row group (8 rows)
    const int row0 = blockIdx.x * TM;
    const int c0 = tc * 4;
    const int r0 = tr * 8;

    float acc[8][4];
#pragma unroll
    for (int i = 0; i < 8; i++)
#pragma unroll
        for (int j = 0; j < 4; j++) acc[i][j] = 0.f;

    for (int kc0 = 0; kc0 < K; kc0 += KC) {
        // stage A chunk [64][KC]
#pragma unroll
        for (int ei = tid; ei < TM * KC; ei += 256) {
            int r = ei / KC;
            int k = ei % KC;
            int row = row0 + r;
            int gk = kc0 + k;
            float v = 0.f;
            if (row < nrows) {
                if (AMODE == 0) {
                    v = A[row * K + gk];
                } else if (AMODE == 1) {
                    if (gk < H)          v = X[snd[row] * H + gk];
                    else if (gk < 2 * H) v = X[rcv[row] * H + (gk - H)];
                    else                 v = Ebuf[row * H + (gk - 2 * H)];
                } else {
                    v = (gk < H) ? X[row * H + gk] : AGG[row * H + (gk - H)];
                }
            }
            As[r * STRIDE + k] = v;
        }
        // stage B chunk [KC][128]
#pragma unroll
        for (int i4 = tid; i4 < KC * H / 4; i4 += 256) {
            int k = i4 >> 5;
            int cq = i4 & 31;
            float4 bv = *reinterpret_cast<const float4*>(&B[(kc0 + k) * H + cq * 4]);
            *reinterpret_cast<float4*>(&Bs[k * H + cq * 4]) = bv;
        }
        __syncthreads();

#pragma unroll
        for (int k = 0; k < KC; k += 4) {
            float4 av[8];
#pragma unroll
            for (int i = 0; i < 8; i++)
                av[i] = *reinterpret_cast<const float4*>(&As[(r0 + i) * STRIDE + k]);
            float4 bv[4];
#pragma unroll
            for (int kk = 0; kk < 4; kk++)
                bv[kk] = *reinterpret_cast<const float4*>(&Bs[(k + kk) * H + c0]);
#pragma unroll
            for (int i = 0; i < 8; i++) {
                const float a0 = av[i].x, a1 = av[i].y, a2 = av[i].z, a3 = av[i].w;
                acc[i][0] += a0 * bv[0].x + a1 * bv[1].x + a2 * bv[2].x + a3 * bv[3].x;
                acc[i][1] += a0 * bv[0].y + a1 * bv[1].y + a2 * bv[2].y + a3 * bv[3].y;
                acc[i][2] += a0 * bv[0].z + a1 * bv[1].z + a2 * bv[2].z + a3 * bv[3].z;
                acc[i][3] += a0 * bv[0].w + a1 * bv[1].w + a2 * bv[2].w + a3 * bv[3].w;
            }
        }
        __syncthreads();
    }

    // epilogue
    float bb[4];
#pragma unroll
    for (int j = 0; j < 4; j++) bb[j] = bias[c0 + j];
    float gg[4], be[4];
    if (EPI >= 1) {
#pragma unroll
        for (int j = 0; j < 4; j++) { gg[j] = lng[c0 + j]; be[j] = lnb[c0 + j]; }
    }

#pragma unroll
    for (int i = 0; i < 8; i++) {
        int row = row0 + r0 + i;
        if (EPI == 0) {
            if (row < nrows) {
#pragma unroll
                for (int j = 0; j < 4; j++) {
                    float v = acc[i][j] + bb[j];
                    out[row * H + c0 + j] = v > 0.f ? v : 0.f;
                }
            }
        } else {
            float v[4];
            float s = 0.f, s2 = 0.f;
#pragma unroll
            for (int j = 0; j < 4; j++) {
                v[j] = acc[i][j] + bb[j];
                s += v[j];
                s2 += v[j] * v[j];
            }
            // row reduction across 32 lanes (same row group lives in one 32-lane half)
#pragma unroll
            for (int m = 1; m < 32; m <<= 1) {
                s += __shfl_xor(s, m);
                s2 += __shfl_xor(s2, m);
            }
            float mean = s * (1.f / H);
            float var = s2 * (1.f / H) - mean * mean;
            float rstd = rsqrtf(var + LN_EPS);
            if (row < nrows) {
                int rb = 0;
                if (EPI == 3) rb = rcv[row];
#pragma unroll
                for (int j = 0; j < 4; j++) {
                    float o = (v[j] - mean) * rstd * gg[j] + be[j];
                    if (EPI == 1) {
                        out[row * H + c0 + j] = o;
                    } else if (EPI == 2) {
                        out[row * H + c0 + j] += o;
                    } else {
                        eout[row * H + c0 + j] += o;
                        atomicAdd(&agg_out[rb * H + c0 + j], o);
                    }
                }
            }
        }
    }
}

// ---------------- decoder ----------------
__global__ void decoder_kernel(const float* __restrict__ x,
                               const float* __restrict__ frames,
                               const float* __restrict__ W1, const float* __restrict__ b1,
                               const float* __restrict__ W2, const float* __restrict__ b2,
                               const float* __restrict__ omean, const float* __restrict__ ostd,
                               float* __restrict__ outp) {
    __shared__ float xr[H];
    __shared__ float hr[H];
    __shared__ float red[2][2];
    int n = blockIdx.x;
    int t = threadIdx.x;  // 128 threads
    xr[t] = x[n * H + t];
    __syncthreads();
    float acc = 0.f;
#pragma unroll 8
    for (int k = 0; k < H; k++) acc += xr[k] * W1[k * H + t];
    hr[t] = fmaxf(acc + b1[t], 0.f);
    __syncthreads();
    float p0 = hr[t] * W2[t * 2 + 0];
    float p1 = hr[t] * W2[t * 2 + 1];
#pragma unroll
    for (int m = 1; m < 64; m <<= 1) {
        p0 += __shfl_xor(p0, m);
        p1 += __shfl_xor(p1, m);
    }
    if ((t & 63) == 0) { red[t >> 6][0] = p0; red[t >> 6][1] = p1; }
    __syncthreads();
    if (t < 2) {
        float d = red[0][t] + red[1][t] + b2[t];
        outp[n * 2 + t] = frames[n * 2 + t] + d * ostd[t] + omean[t];
    }
}

// ---------------- launch ----------------
extern "C" void kernel_launch(void* const* d_in, const int* in_sizes, int n_in,
                              void* d_out, int out_size, void* d_ws, size_t ws_size,
                              hipStream_t stream) {
    (void)in_sizes; (void)n_in; (void)out_size; (void)ws_size;
    const int*   node_type  = (const int*)  d_in[0];
    const int*   edge_index = (const int*)  d_in[1];
    const float* frames     = (const float*)d_in[2];
    const float* edge_feats = (const float*)d_in[3];
    const float* nmean      = (const float*)d_in[4];
    const float* nstd       = (const float*)d_in[5];
    const float* omean      = (const float*)d_in[6];
    const float* ostd       = (const float*)d_in[7];
    const float* enc_nW1    = (const float*)d_in[8];
    const float* enc_nb1    = (const float*)d_in[9];
    const float* enc_nW2    = (const float*)d_in[10];
    const float* enc_nb2    = (const float*)d_in[11];
    const float* enc_nlng   = (const float*)d_in[12];
    const float* enc_nlnb   = (const float*)d_in[13];
    const float* enc_eW1    = (const float*)d_in[14];
    const float* enc_eb1    = (const float*)d_in[15];
    const float* enc_eW2    = (const float*)d_in[16];
    const float* enc_eb2    = (const float*)d_in[17];
    const float* enc_elng   = (const float*)d_in[18];
    const float* enc_elnb   = (const float*)d_in[19];
    const float* eb_W1      = (const float*)d_in[20];
    const float* eb_b1      = (const float*)d_in[21];
    const float* eb_W2      = (const float*)d_in[22];
    const float* eb_b2      = (const float*)d_in[23];
    const float* eb_g       = (const float*)d_in[24];
    const float* eb_bn      = (const float*)d_in[25];
    const float* nb_W1      = (const float*)d_in[26];
    const float* nb_b1      = (const float*)d_in[27];
    const float* nb_W2      = (const float*)d_in[28];
    const float* nb_b2      = (const float*)d_in[29];
    const float* nb_g       = (const float*)d_in[30];
    const float* nb_bn      = (const float*)d_in[31];
    const float* dec_W1     = (const float*)d_in[32];
    const float* dec_b1     = (const float*)d_in[33];
    const float* dec_W2     = (const float*)d_in[34];
    const float* dec_b2     = (const float*)d_in[35];

    const int* snd = edge_index;
    const int* rcv = edge_index + N_EDGES;

    float* ws  = (float*)d_ws;
    float* x   = ws;                    // N*128
    float* e   = x + N_NODES * H;       // E*128
    float* h   = e + N_EDGES * H;       // E*128
    float* agg = h + N_EDGES * H;       // N*128
    float* a16 = agg + N_NODES * H;     // N*16
    float* a4  = a16 + N_NODES * 16;    // E*4
    float* w16 = a4 + N_EDGES * 4;      // 16*128
    float* w4  = w16 + 16 * H;          // 4*128

    // prep
    prep_node_attr<<<(N_NODES * 16 + 255) / 256, 256, 0, stream>>>(node_type, frames, nmean, nstd, a16);
    prep_edge_attr<<<(N_EDGES * 4 + 255) / 256, 256, 0, stream>>>(edge_feats, a4);
    prep_pad_w<<<(16 * H + 255) / 256, 256, 0, stream>>>(enc_nW1, w16, 11, 16);
    prep_pad_w<<<(4 * H + 255) / 256, 256, 0, stream>>>(enc_eW1, w4, 3, 4);

    const int gN = (N_NODES + 63) / 64;
    const int gE = (N_EDGES + 63) / 64;
    const float* np_ = nullptr;
    const int* ni_ = nullptr;
    float* npm_ = nullptr;

    // encoder: nodes
    gemm_fused<16, 16, 0, 0><<<gN, 256, 0, stream>>>(a16, np_, np_, np_, ni_, ni_,
        w16, enc_nb1, np_, np_, h, npm_, npm_, N_NODES);
    gemm_fused<128, 32, 0, 1><<<gN, 256, 0, stream>>>(h, np_, np_, np_, ni_, ni_,
        enc_nW2, enc_nb2, enc_nlng, enc_nlnb, x, npm_, npm_, N_NODES);
    // encoder: edges
    gemm_fused<4, 4, 0, 0><<<gE, 256, 0, stream>>>(a4, np_, np_, np_, ni_, ni_,
        w4, enc_eb1, np_, np_, h, npm_, npm_, N_EDGES);
    gemm_fused<128, 32, 0, 1><<<gE, 256, 0, stream>>>(h, np_, np_, np_, ni_, ni_,
        enc_eW2, enc_eb2, enc_elng, enc_elnb, e, npm_, npm_, N_EDGES);

    for (int l = 0; l < NLAYERS; l++) {
        hipMemsetAsync(agg, 0, (size_t)N_NODES * H * sizeof(float), stream);
        // EdgeBlock MLP1: [E,384] -> h (relu)
        gemm_fused<384, 32, 1, 0><<<gE, 256, 0, stream>>>(np_, x, e, np_, snd, rcv,
            eb_W1 + (size_t)l * 384 * H, eb_b1 + l * H, np_, np_, h, npm_, npm_, N_EDGES);
        // EdgeBlock MLP2 + LN + residual + scatter-add agg
        gemm_fused<128, 32, 0, 3><<<gE, 256, 0, stream>>>(h, np_, np_, np_, ni_, rcv,
            eb_W2 + (size_t)l * H * H, eb_b2 + l * H, eb_g + l * H, eb_bn + l * H,
            npm_, e, agg, N_EDGES);
        // NodeBlock MLP1: [N,256] -> h (relu)
        gemm_fused<256, 32, 2, 0><<<gN, 256, 0, stream>>>(np_, x, np_, agg, ni_, ni_,
            nb_W1 + (size_t)l * 2 * H * H, nb_b1 + l * H, np_, np_, h, npm_, npm_, N_NODES);
        // NodeBlock MLP2 + LN + residual into x
        gemm_fused<128, 32, 0, 2><<<gN, 256, 0, stream>>>(h, np_, np_, np_, ni_, ni_,
            nb_W2 + (size_t)l * H * H, nb_b2 + l * H, nb_g + l * H, nb_bn + l * H,
            x, npm_, npm_, N_NODES);
    }

    decoder_kernel<<<N_NODES, 128, 0, stream>>>(x, frames, dec_W1, dec_b1, dec_W2, dec_b2,
                                                omean, ostd, (float*)d_out);
}

// Round 2
// 1460.254 us; speedup vs baseline: 6.3259x; 6.3259x over previous
//
#include <hip/hip_runtime.h>
#include <hip/hip_bf16.h>

#define N_NODES 10000
#define N_EDGES 70000
#define NPAD 10112   // 158*64
#define EPAD 70016   // 547*128
#define H 128
#define NLAYERS 15
constexpr float LN_EPS = 1e-5f;

typedef __attribute__((ext_vector_type(8))) short short8;
typedef __attribute__((ext_vector_type(4))) float f32x4;

__device__ __forceinline__ float bf2f(unsigned int ulo16) {
    return __uint_as_float(ulo16 << 16);
}
__device__ __forceinline__ unsigned short f2bf(float f) {
    unsigned int x = __float_as_uint(f);
    x += 0x7fffu + ((x >> 16) & 1u);
    return (unsigned short)(x >> 16);
}

// ---------------- prep kernels ----------------
__global__ void prep_node(const int* __restrict__ nt, const float* __restrict__ frames,
                          const float* __restrict__ nm, const float* __restrict__ ns,
                          unsigned short* __restrict__ a16b) {
    int i = blockIdx.x * blockDim.x + threadIdx.x;
    if (i >= NPAD * 32) return;
    int n = i >> 5, k = i & 31;
    float v = 0.f;
    if (n < N_NODES && k < 11) {
        float raw = (k < 2) ? frames[n * 2 + k] : ((nt[n] == (k - 2)) ? 1.f : 0.f);
        v = (raw - nm[k]) / ns[k];
    }
    a16b[i] = f2bf(v);
}

__global__ void prep_edge(const float* __restrict__ ef, unsigned short* __restrict__ a4b) {
    int i = blockIdx.x * blockDim.x + threadIdx.x;
    if (i >= EPAD * 32) return;
    int e = i >> 5, k = i & 31;
    float v = (e < N_EDGES && k < 3) ? ef[e * 3 + k] : 0.f;
    a4b[i] = f2bf(v);
}

// W[nmat][Kr][128] fp32 -> Wt[nmat][128][Kp] bf16 (zero-pad k>=Kr)
__global__ void transpose_w(const float* __restrict__ w, unsigned short* __restrict__ wt,
                            int Kr, int Kp, int nmat) {
    int i = blockIdx.x * blockDim.x + threadIdx.x;
    int total = nmat * 128 * Kp;
    if (i >= total) return;
    int m = i / (128 * Kp);
    int r = i % (128 * Kp);
    int c = r / Kp;
    int k = r % Kp;
    float v = (k < Kr) ? w[((size_t)m * Kr + k) * H + c] : 0.f;
    wt[i] = f2bf(v);
}

// ---------------- CSR build ----------------
__global__ void hist_kernel(const int* __restrict__ rcv, int* __restrict__ counts) {
    int j = blockIdx.x * blockDim.x + threadIdx.x;
    if (j < N_EDGES) atomicAdd(&counts[rcv[j]], 1);
}

__global__ void scan_kernel(const int* __restrict__ counts, int* __restrict__ starts) {
    __shared__ int part[1024];
    const int CH = 10;  // 1024*10 >= 10000
    int t = threadIdx.x;
    int base = t * CH;
    int loc[CH];
    int s = 0;
#pragma unroll
    for (int i = 0; i < CH; i++) {
        int idx = base + i;
        int c = (idx < N_NODES) ? counts[idx] : 0;
        loc[i] = s;
        s += c;
    }
    part[t] = s;
    __syncthreads();
    for (int off = 1; off < 1024; off <<= 1) {
        int v = (t >= off) ? part[t - off] : 0;
        __syncthreads();
        part[t] += v;
        __syncthreads();
    }
    int pre = (t > 0) ? part[t - 1] : 0;
#pragma unroll
    for (int i = 0; i < CH; i++) {
        int idx = base + i;
        if (idx < N_NODES) starts[idx] = pre + loc[i];
    }
}

__global__ void scatter_kernel(const int* __restrict__ rcv, const int* __restrict__ starts,
                               int* __restrict__ cursor, int* __restrict__ esorted) {
    int j = blockIdx.x * blockDim.x + threadIdx.x;
    if (j >= N_EDGES) return;
    int r = rcv[j];
    int p = starts[r] + atomicAdd(&cursor[r], 1);
    esorted[p] = j;
}

// ---------------- segmented aggregation (replaces atomics) ----------------
__global__ void agg_kernel(const unsigned short* __restrict__ enew,
                           const int* __restrict__ esorted,
                           const int* __restrict__ starts,
                           const int* __restrict__ counts,
                           unsigned short* __restrict__ aggb) {
    int n = blockIdx.x * 8 + (threadIdx.x >> 5);
    int l = threadIdx.x & 31;  // 4 cols each
    if (n >= N_NODES) return;
    float a0 = 0.f, a1 = 0.f, a2 = 0.f, a3 = 0.f;
    int s0 = starts[n], cnt = counts[n];
    for (int j = 0; j < cnt; ++j) {
        int e = esorted[s0 + j];
        uint2 v = *reinterpret_cast<const uint2*>(enew + (size_t)e * H + l * 4);
        a0 += bf2f(v.x & 0xffffu);
        a1 += bf2f(v.x >> 16);
        a2 += bf2f(v.y & 0xffffu);
        a3 += bf2f(v.y >> 16);
    }
    uint2 o;
    o.x = (unsigned int)f2bf(a0) | ((unsigned int)f2bf(a1) << 16);
    o.y = (unsigned int)f2bf(a2) | ((unsigned int)f2bf(a3) << 16);
    *reinterpret_cast<uint2*>(aggb + (size_t)n * H + l * 4) = o;
}

// ---------------- fused MFMA GEMM ----------------
// Block: 256 thr = 4 waves; wave tile = (16*WR rows) x 128 cols; BM = 64*WR.
// MFMA 16x16x32 bf16. A-frag: row=lane&15, k=(lane>>4)*8+j. B-frag from Bt
// [col][k] layout: col=lane&15, k=(lane>>4)*8+j. D: col=lane&15, row=(lane>>4)*4+r.
// AMODE: 0 plain A[rows][K]; 1 edge concat(x[snd],x[rcv],e); 2 node concat(x,agg)
// EPI: 0 bias+relu -> out_bf
//      1 bias+LN   -> out_fp, out_bf
//      2 bias+LN   -> out_fp += o; out_bf = bf16(new)    (node residual)
//      3 bias+LN   -> out_fp += o; out_bf = bf16(new); enew_bf = bf16(o)
template <int K, int AMODE, int EPI, int WR>
__launch_bounds__(256)
__global__ void gemm_mfma(const unsigned short* __restrict__ A,
                          const unsigned short* __restrict__ Xb,
                          const unsigned short* __restrict__ Eb,
                          const unsigned short* __restrict__ Gb,
                          const int* __restrict__ snd,
                          const int* __restrict__ rcv,
                          const unsigned short* __restrict__ Bt,
                          const float* __restrict__ bias,
                          const float* __restrict__ lng,
                          const float* __restrict__ lnb,
                          unsigned short* __restrict__ out_bf,
                          float* __restrict__ out_fp,
                          unsigned short* __restrict__ enew_bf,
                          int nrows) {
    constexpr int BK = (K >= 64) ? 64 : K;   // 64 or 32
    constexpr int SA = BK + 8;               // padded stride (16B-aligned rows)
    constexpr int BM = 64 * WR;
    constexpr int KSTEP = BK / 32;
    __shared__ __attribute__((aligned(16))) unsigned short As[BM * SA];
    __shared__ __attribute__((aligned(16))) unsigned short Bs[H * SA];

    const int tid = threadIdx.x;
    const int wave = tid >> 6;
    const int lane = tid & 63;
    const int l15 = lane & 15;
    const int lhi = lane >> 4;
    const int row0 = blockIdx.x * BM;
    const int wrow = wave * 16 * WR;

    f32x4 acc[WR][8];
#pragma unroll
    for (int i = 0; i < WR; i++)
#pragma unroll
        for (int j = 0; j < 8; j++) acc[i][j] = (f32x4){0.f, 0.f, 0.f, 0.f};

    for (int kc = 0; kc < K; kc += BK) {
        constexpr int KQ = BK / 8;
        constexpr int LPT_A = BM * BK / 8 / 256;
#pragma unroll
        for (int it = 0; it < LPT_A; ++it) {
            int q = tid + it * 256;
            int r = q / KQ;
            int kq = q % KQ;
            int gk = kc + kq * 8;
            int grow = row0 + r;
            const unsigned short* src;
            if (AMODE == 0) {
                src = A + (size_t)grow * K + gk;
            } else if (AMODE == 1) {
                int e = (grow < nrows) ? grow : 0;
                if (gk < H)          src = Xb + (size_t)snd[e] * H + gk;
                else if (gk < 2 * H) src = Xb + (size_t)rcv[e] * H + (gk - H);
                else                 src = Eb + (size_t)grow * H + (gk - 2 * H);
            } else {
                if (gk < H) src = Xb + (size_t)grow * H + gk;
                else        src = Gb + (size_t)grow * H + (gk - H);
            }
            uint4 v = *reinterpret_cast<const uint4*>(src);
            *reinterpret_cast<uint4*>(&As[r * SA + kq * 8]) = v;
        }
        constexpr int LPT_B = H * BK / 8 / 256;
#pragma unroll
        for (int it = 0; it < LPT_B; ++it) {
            int q = tid + it * 256;
            int c = q / KQ;
            int kq = q % KQ;
            uint4 v = *reinterpret_cast<const uint4*>(Bt + (size_t)c * K + kc + kq * 8);
            *reinterpret_cast<uint4*>(&Bs[c * SA + kq * 8]) = v;
        }
        __syncthreads();
#pragma unroll
        for (int ks = 0; ks < KSTEP; ++ks) {
            short8 af[WR];
#pragma unroll
            for (int i = 0; i < WR; ++i)
                af[i] = *reinterpret_cast<const short8*>(
                    &As[(wrow + i * 16 + l15) * SA + ks * 32 + lhi * 8]);
#pragma unroll
            for (int j = 0; j < 8; ++j) {
                short8 bfr = *reinterpret_cast<const short8*>(
                    &Bs[(j * 16 + l15) * SA + ks * 32 + lhi * 8]);
#pragma unroll
                for (int i = 0; i < WR; ++i)
                    acc[i][j] = __builtin_amdgcn_mfma_f32_16x16x32_bf16(af[i], bfr, acc[i][j], 0, 0, 0);
            }
        }
        __syncthreads();
    }

    // ---- epilogue ----
    float bv[8], gv[8], lv[8];
#pragma unroll
    for (int j = 0; j < 8; ++j) {
        bv[j] = bias[j * 16 + l15];
        if (EPI >= 1) { gv[j] = lng[j * 16 + l15]; lv[j] = lnb[j * 16 + l15]; }
    }

#pragma unroll
    for (int i = 0; i < WR; ++i) {
#pragma unroll
        for (int r = 0; r < 4; ++r) {
            int row = row0 + wrow + i * 16 + lhi * 4 + r;
            if (EPI == 0) {
                if (row < nrows) {
#pragma unroll
                    for (int j = 0; j < 8; ++j) {
                        float v = acc[i][j][r] + bv[j];
                        v = v > 0.f ? v : 0.f;
                        out_bf[(size_t)row * H + j * 16 + l15] = f2bf(v);
                    }
                }
            } else {
                float v[8];
                float s = 0.f, s2 = 0.f;
#pragma unroll
                for (int j = 0; j < 8; ++j) {
                    v[j] = acc[i][j][r] + bv[j];
                    s += v[j];
                    s2 += v[j] * v[j];
                }
#pragma unroll
                for (int m = 1; m < 16; m <<= 1) {
                    s += __shfl_xor(s, m);
                    s2 += __shfl_xor(s2, m);
                }
                float mean = s * (1.f / 128.f);
                float var = s2 * (1.f / 128.f) - mean * mean;
                float rstd = rsqrtf(var + LN_EPS);
                if (row < nrows) {
#pragma unroll
                    for (int j = 0; j < 8; ++j) {
                        float o = (v[j] - mean) * rstd * gv[j] + lv[j];
                        size_t off = (size_t)row * H + j * 16 + l15;
                        if (EPI == 1) {
                            out_fp[off] = o;
                            out_bf[off] = f2bf(o);
                        } else if (EPI == 2) {
                            float nx = out_fp[off] + o;
                            out_fp[off] = nx;
                            out_bf[off] = f2bf(nx);
                        } else {
                            float ne = out_fp[off] + o;
                            out_fp[off] = ne;
                            out_bf[off] = f2bf(ne);
                            enew_bf[off] = f2bf(o);
                        }
                    }
                }
            }
        }
    }
}

// ---------------- decoder (fp32, small) ----------------
__global__ void decoder_kernel(const float* __restrict__ x,
                               const float* __restrict__ frames,
                               const float* __restrict__ W1, const float* __restrict__ b1,
                               const float* __restrict__ W2, const float* __restrict__ b2,
                               const float* __restrict__ omean, const float* __restrict__ ostd,
                               float* __restrict__ outp) {
    __shared__ float xr[H];
    __shared__ float hr[H];
    __shared__ float red[2][2];
    int n = blockIdx.x;
    int t = threadIdx.x;  // 128 threads
    xr[t] = x[n * H + t];
    __syncthreads();
    float acc = 0.f;
#pragma unroll 8
    for (int k = 0; k < H; k++) acc += xr[k] * W1[k * H + t];
    hr[t] = fmaxf(acc + b1[t], 0.f);
    __syncthreads();
    float p0 = hr[t] * W2[t * 2 + 0];
    float p1 = hr[t] * W2[t * 2 + 1];
#pragma unroll
    for (int m = 1; m < 64; m <<= 1) {
        p0 += __shfl_xor(p0, m);
        p1 += __shfl_xor(p1, m);
    }
    if ((t & 63) == 0) { red[t >> 6][0] = p0; red[t >> 6][1] = p1; }
    __syncthreads();
    if (t < 2) {
        float d = red[0][t] + red[1][t] + b2[t];
        outp[n * 2 + t] = frames[n * 2 + t] + d * ostd[t] + omean[t];
    }
}

// ---------------- launch ----------------
extern "C" void kernel_launch(void* const* d_in, const int* in_sizes, int n_in,
                              void* d_out, int out_size, void* d_ws, size_t ws_size,
                              hipStream_t stream) {
    (void)in_sizes; (void)n_in; (void)out_size; (void)ws_size;
    const int*   node_type  = (const int*)  d_in[0];
    const int*   edge_index = (const int*)  d_in[1];
    const float* frames     = (const float*)d_in[2];
    const float* edge_feats = (const float*)d_in[3];
    const float* nmean      = (const float*)d_in[4];
    const float* nstd       = (const float*)d_in[5];
    const float* omean      = (const float*)d_in[6];
    const float* ostd       = (const float*)d_in[7];
    const float* enc_nW1    = (const float*)d_in[8];
    const float* enc_nb1    = (const float*)d_in[9];
    const float* enc_nW2    = (const float*)d_in[10];
    const float* enc_nb2    = (const float*)d_in[11];
    const float* enc_nlng   = (const float*)d_in[12];
    const float* enc_nlnb   = (const float*)d_in[13];
    const float* enc_eW1    = (const float*)d_in[14];
    const float* enc_eb1    = (const float*)d_in[15];
    const float* enc_eW2    = (const float*)d_in[16];
    const float* enc_eb2    = (const float*)d_in[17];
    const float* enc_elng   = (const float*)d_in[18];
    const float* enc_elnb   = (const float*)d_in[19];
    const float* eb_W1      = (const float*)d_in[20];
    const float* eb_b1      = (const float*)d_in[21];
    const float* eb_W2      = (const float*)d_in[22];
    const float* eb_b2      = (const float*)d_in[23];
    const float* eb_g       = (const float*)d_in[24];
    const float* eb_bn      = (const float*)d_in[25];
    const float* nb_W1      = (const float*)d_in[26];
    const float* nb_b1      = (const float*)d_in[27];
    const float* nb_W2      = (const float*)d_in[28];
    const float* nb_b2      = (const float*)d_in[29];
    const float* nb_g       = (const float*)d_in[30];
    const float* nb_bn      = (const float*)d_in[31];
    const float* dec_W1     = (const float*)d_in[32];
    const float* dec_b1     = (const float*)d_in[33];
    const float* dec_W2     = (const float*)d_in[34];
    const float* dec_b2     = (const float*)d_in[35];

    const int* snd = edge_index;
    const int* rcv = edge_index + N_EDGES;

    // ---- workspace layout ----
    char* p = (char*)d_ws;
    auto alloc = [&](size_t bytes) {
        void* r = (void*)p;
        p += (bytes + 255) & ~(size_t)255;
        return r;
    };
    float* x_fp  = (float*)alloc((size_t)NPAD * H * 4);
    float* e_fp  = (float*)alloc((size_t)EPAD * H * 4);
    unsigned short* x_bf   = (unsigned short*)alloc((size_t)NPAD * H * 2);
    unsigned short* e_bf   = (unsigned short*)alloc((size_t)EPAD * H * 2);
    unsigned short* enew   = (unsigned short*)alloc((size_t)EPAD * H * 2);
    unsigned short* h_bf   = (unsigned short*)alloc((size_t)EPAD * H * 2);
    unsigned short* agg_bf = (unsigned short*)alloc((size_t)NPAD * H * 2);
    unsigned short* a16b   = (unsigned short*)alloc((size_t)NPAD * 32 * 2);
    unsigned short* a4b    = (unsigned short*)alloc((size_t)EPAD * 32 * 2);
    unsigned short* wt_en1 = (unsigned short*)alloc((size_t)128 * 32 * 2);
    unsigned short* wt_ee1 = (unsigned short*)alloc((size_t)128 * 32 * 2);
    unsigned short* wt_en2 = (unsigned short*)alloc((size_t)128 * 128 * 2);
    unsigned short* wt_ee2 = (unsigned short*)alloc((size_t)128 * 128 * 2);
    unsigned short* wt_eb1 = (unsigned short*)alloc((size_t)NLAYERS * 128 * 384 * 2);
    unsigned short* wt_eb2 = (unsigned short*)alloc((size_t)NLAYERS * 128 * 128 * 2);
    unsigned short* wt_nb1 = (unsigned short*)alloc((size_t)NLAYERS * 128 * 256 * 2);
    unsigned short* wt_nb2 = (unsigned short*)alloc((size_t)NLAYERS * 128 * 128 * 2);
    int* counts  = (int*)alloc((size_t)N_NODES * 4);
    int* starts  = (int*)alloc((size_t)N_NODES * 4);
    int* cursor  = (int*)alloc((size_t)N_NODES * 4);
    int* esorted = (int*)alloc((size_t)N_EDGES * 4);

    // ---- prep ----
    prep_node<<<(NPAD * 32 + 255) / 256, 256, 0, stream>>>(node_type, frames, nmean, nstd, a16b);
    prep_edge<<<(EPAD * 32 + 255) / 256, 256, 0, stream>>>(edge_feats, a4b);
    auto tw = [&](const float* w, unsigned short* wt, int Kr, int Kp, int nmat) {
        int total = nmat * 128 * Kp;
        transpose_w<<<(total + 255) / 256, 256, 0, stream>>>(w, wt, Kr, Kp, nmat);
    };
    tw(enc_nW1, wt_en1, 11, 32, 1);
    tw(enc_eW1, wt_ee1, 3, 32, 1);
    tw(enc_nW2, wt_en2, 128, 128, 1);
    tw(enc_eW2, wt_ee2, 128, 128, 1);
    tw(eb_W1, wt_eb1, 384, 384, NLAYERS);
    tw(eb_W2, wt_eb2, 128, 128, NLAYERS);
    tw(nb_W1, wt_nb1, 256, 256, NLAYERS);
    tw(nb_W2, wt_nb2, 128, 128, NLAYERS);

    // ---- CSR ----
    hipMemsetAsync(counts, 0, (size_t)N_NODES * 4, stream);
    hipMemsetAsync(cursor, 0, (size_t)N_NODES * 4, stream);
    hist_kernel<<<(N_EDGES + 255) / 256, 256, 0, stream>>>(rcv, counts);
    scan_kernel<<<1, 1024, 0, stream>>>(counts, starts);
    scatter_kernel<<<(N_EDGES + 255) / 256, 256, 0, stream>>>(rcv, starts, cursor, esorted);

    const int gE = EPAD / 128;  // 547
    const int gN = NPAD / 64;   // 158
    const unsigned short* nu_ = nullptr;
    const int* ni_ = nullptr;
    const float* nf_ = nullptr;
    unsigned short* nm_ = nullptr;
    float* nfm_ = nullptr;

    // ---- encoder ----
    gemm_mfma<32, 0, 0, 1><<<gN, 256, 0, stream>>>(a16b, nu_, nu_, nu_, ni_, ni_,
        wt_en1, enc_nb1, nf_, nf_, h_bf, nfm_, nm_, N_NODES);
    gemm_mfma<128, 0, 1, 1><<<gN, 256, 0, stream>>>(h_bf, nu_, nu_, nu_, ni_, ni_,
        wt_en2, enc_nb2, enc_nlng, enc_nlnb, x_bf, x_fp, nm_, N_NODES);
    gemm_mfma<32, 0, 0, 2><<<gE, 256, 0, stream>>>(a4b, nu_, nu_, nu_, ni_, ni_,
        wt_ee1, enc_eb1, nf_, nf_, h_bf, nfm_, nm_, N_EDGES);
    gemm_mfma<128, 0, 1, 2><<<gE, 256, 0, stream>>>(h_bf, nu_, nu_, nu_, ni_, ni_,
        wt_ee2, enc_eb2, enc_elng, enc_elnb, e_bf, e_fp, nm_, N_EDGES);

    // ---- processor ----
    for (int l = 0; l < NLAYERS; ++l) {
        gemm_mfma<384, 1, 0, 2><<<gE, 256, 0, stream>>>(nu_, x_bf, e_bf, nu_, snd, rcv,
            wt_eb1 + (size_t)l * 128 * 384, eb_b1 + l * H, nf_, nf_,
            h_bf, nfm_, nm_, N_EDGES);
        gemm_mfma<128, 0, 3, 2><<<gE, 256, 0, stream>>>(h_bf, nu_, nu_, nu_, ni_, ni_,
            wt_eb2 + (size_t)l * 128 * 128, eb_b2 + l * H, eb_g + l * H, eb_bn + l * H,
            e_bf, e_fp, enew, N_EDGES);
        agg_kernel<<<(N_NODES + 7) / 8, 256, 0, stream>>>(enew, esorted, starts, counts, agg_bf);
        gemm_mfma<256, 2, 0, 1><<<gN, 256, 0, stream>>>(nu_, x_bf, nu_, agg_bf, ni_, ni_,
            wt_nb1 + (size_t)l * 128 * 256, nb_b1 + l * H, nf_, nf_,
            h_bf, nfm_, nm_, N_NODES);
        gemm_mfma<128, 0, 2, 1><<<gN, 256, 0, stream>>>(h_bf, nu_, nu_, nu_, ni_, ni_,
            wt_nb2 + (size_t)l * 128 * 128, nb_b2 + l * H, nb_g + l * H, nb_bn + l * H,
            x_bf, x_fp, nm_, N_NODES);
    }

    decoder_kernel<<<N_NODES, 128, 0, stream>>>(x_fp, frames, dec_W1, dec_b1, dec_W2, dec_b2,
                                                omean, ostd, (float*)d_out);
}

// Round 4
// 1180.501 us; speedup vs baseline: 7.8250x; 1.2370x over previous
//
#include <hip/hip_runtime.h>
#include <hip/hip_bf16.h>

#define N_NODES 10000
#define N_EDGES 70000
#define NPAD 10112   // 158*64
#define EPAD 70016   // 547*128
#define H 128
#define NLAYERS 15
constexpr float LN_EPS = 1e-5f;

typedef __attribute__((ext_vector_type(8))) short short8;
typedef __attribute__((ext_vector_type(4))) float f32x4;

__device__ __forceinline__ float bf2f(unsigned int ulo16) {
    return __uint_as_float(ulo16 << 16);
}
__device__ __forceinline__ unsigned short f2bf(float f) {
    unsigned int x = __float_as_uint(f);
    x += 0x7fffu + ((x >> 16) & 1u);
    return (unsigned short)(x >> 16);
}

// ---------------- prep kernels ----------------
__global__ void prep_node(const int* __restrict__ nt, const float* __restrict__ frames,
                          const float* __restrict__ nm, const float* __restrict__ ns,
                          unsigned short* __restrict__ a16b) {
    int i = blockIdx.x * blockDim.x + threadIdx.x;
    if (i >= NPAD * 32) return;
    int n = i >> 5, k = i & 31;
    float v = 0.f;
    if (n < N_NODES && k < 11) {
        float raw = (k < 2) ? frames[n * 2 + k] : ((nt[n] == (k - 2)) ? 1.f : 0.f);
        v = (raw - nm[k]) / ns[k];
    }
    a16b[i] = f2bf(v);
}

__global__ void prep_edge(const float* __restrict__ ef, unsigned short* __restrict__ a4b) {
    int i = blockIdx.x * blockDim.x + threadIdx.x;
    if (i >= EPAD * 32) return;
    int e = i >> 5, k = i & 31;
    float v = (e < N_EDGES && k < 3) ? ef[e * 3 + k] : 0.f;
    a4b[i] = f2bf(v);
}

// W[nmat][Kr][128] fp32 -> Wt[nmat][128][Kp] bf16 (zero-pad k>=Kr), LDS-tiled.
__global__ void transpose_w_tiled(const float* __restrict__ w, unsigned short* __restrict__ wt,
                                  int Kr, int Kp, int nmat) {
    __shared__ float T[32][33];
    int nkt = Kp / 32;
    int bid = blockIdx.x;
    int m = bid / (nkt * 4);
    int rest = bid % (nkt * 4);
    int kt = rest / 4, ct = rest % 4;
    int t = threadIdx.x;
    int tc = t & 31, tr = t >> 5;  // tr 0..7
#pragma unroll
    for (int rr = 0; rr < 4; ++rr) {
        int k = kt * 32 + tr + rr * 8;
        int c = ct * 32 + tc;
        T[tr + rr * 8][tc] = (k < Kr) ? w[((size_t)m * Kr + k) * H + c] : 0.f;
    }
    __syncthreads();
#pragma unroll
    for (int rr = 0; rr < 4; ++rr) {
        int c = ct * 32 + tr + rr * 8;
        int k = kt * 32 + tc;
        wt[((size_t)m * H + c) * Kp + k] = f2bf(T[tc][tr + rr * 8]);
    }
}

// ---------------- CSR build ----------------
__global__ void hist_kernel(const int* __restrict__ rcv, int* __restrict__ counts) {
    int j = blockIdx.x * blockDim.x + threadIdx.x;
    if (j < N_EDGES) atomicAdd(&counts[rcv[j]], 1);
}

__global__ void scan_kernel(const int* __restrict__ counts, int* __restrict__ starts) {
    __shared__ int part[1024];
    const int CH = 10;
    int t = threadIdx.x;
    int base = t * CH;
    int loc[CH];
    int s = 0;
#pragma unroll
    for (int i = 0; i < CH; i++) {
        int idx = base + i;
        int c = (idx < N_NODES) ? counts[idx] : 0;
        loc[i] = s;
        s += c;
    }
    part[t] = s;
    __syncthreads();
    for (int off = 1; off < 1024; off <<= 1) {
        int v = (t >= off) ? part[t - off] : 0;
        __syncthreads();
        part[t] += v;
        __syncthreads();
    }
    int pre = (t > 0) ? part[t - 1] : 0;
#pragma unroll
    for (int i = 0; i < CH; i++) {
        int idx = base + i;
        if (idx < N_NODES) starts[idx] = pre + loc[i];
    }
}

__global__ void scatter_kernel(const int* __restrict__ rcv, const int* __restrict__ starts,
                               int* __restrict__ cursor, int* __restrict__ esorted) {
    int j = blockIdx.x * blockDim.x + threadIdx.x;
    if (j >= N_EDGES) return;
    int r = rcv[j];
    int p = starts[r] + atomicAdd(&cursor[r], 1);
    esorted[p] = j;
}

// ---------------- segmented aggregation ----------------
__global__ void agg_kernel(const unsigned short* __restrict__ enew,
                           const int* __restrict__ esorted,
                           const int* __restrict__ starts,
                           const int* __restrict__ counts,
                           unsigned short* __restrict__ aggb) {
    int n = blockIdx.x * 8 + (threadIdx.x >> 5);
    int l = threadIdx.x & 31;  // 4 cols each
    if (n >= N_NODES) return;
    float a0 = 0.f, a1 = 0.f, a2 = 0.f, a3 = 0.f;
    int s0 = starts[n], cnt = counts[n];
    for (int j = 0; j < cnt; ++j) {
        int e = esorted[s0 + j];
        uint2 v = *reinterpret_cast<const uint2*>(enew + (size_t)e * H + l * 4);
        a0 += bf2f(v.x & 0xffffu);
        a1 += bf2f(v.x >> 16);
        a2 += bf2f(v.y & 0xffffu);
        a3 += bf2f(v.y >> 16);
    }
    uint2 o;
    o.x = (unsigned int)f2bf(a0) | ((unsigned int)f2bf(a1) << 16);
    o.y = (unsigned int)f2bf(a2) | ((unsigned int)f2bf(a3) << 16);
    *reinterpret_cast<uint2*>(aggb + (size_t)n * H + l * 4) = o;
}

// ---------------- fused two-stage MFMA MLP ----------------
// stage1: [BM x K1] @ W1t -> relu -> Hs (LDS, bf16); stage2: Hs @ W2t (K=128) -> epilogue.
// 256 thr = 4 waves; wave tile = 16*WR rows x 128 cols; BM = 64*WR.
// AMODE: 0 plain A[rows][K1]; 1 edge concat(x[snd],x[rcv],e); 2 node concat(x,agg)
// EPI: 1 bias+LN -> out_fp, out_bf
//      2 bias+LN -> out_fp += o; out_bf = bf16(new)           (node residual)
//      3 bias+LN -> out_fp += o; out_bf = bf16(new); enew = bf16(o)
template <int K1, int AMODE, int EPI, int WR>
__launch_bounds__(256)
__global__ void mlp_fused(const unsigned short* __restrict__ A,
                          const unsigned short* __restrict__ Xb,
                          const unsigned short* __restrict__ Eb,
                          const unsigned short* __restrict__ Gb,
                          const int* __restrict__ snd,
                          const int* __restrict__ rcv,
                          const unsigned short* __restrict__ Bt1,
                          const float* __restrict__ bias1,
                          const unsigned short* __restrict__ Bt2,
                          const float* __restrict__ bias2,
                          const float* __restrict__ lng,
                          const float* __restrict__ lnb,
                          unsigned short* __restrict__ out_bf,
                          float* __restrict__ out_fp,
                          unsigned short* __restrict__ enew_bf,
                          int nrows) {
    constexpr int BK1 = (K1 >= 64) ? 64 : K1;
    constexpr int SA = BK1 + 8;
    constexpr int SB = 72;           // stride for B tiles (BK=64 max)
    constexpr int SH = H + 8;        // 136
    constexpr int BM = 64 * WR;
    __shared__ __attribute__((aligned(16))) unsigned short As[BM * SA];
    __shared__ __attribute__((aligned(16))) unsigned short Bs[H * SB];
    __shared__ __attribute__((aligned(16))) unsigned short Hs[BM * SH];

    const int tid = threadIdx.x;
    const int wave = tid >> 6;
    const int lane = tid & 63;
    const int l15 = lane & 15;
    const int lhi = lane >> 4;
    const int row0 = blockIdx.x * BM;
    const int wrow = wave * 16 * WR;

    f32x4 acc[WR][8];
#pragma unroll
    for (int i = 0; i < WR; i++)
#pragma unroll
        for (int j = 0; j < 8; j++) acc[i][j] = (f32x4){0.f, 0.f, 0.f, 0.f};

    // ---- stage 1: K1 loop ----
    for (int kc = 0; kc < K1; kc += BK1) {
        constexpr int KQ = BK1 / 8;
        constexpr int LPT_A = BM * KQ / 256;
#pragma unroll
        for (int it = 0; it < LPT_A; ++it) {
            int q = tid + it * 256;
            int r = q / KQ;
            int kq = q % KQ;
            int gk = kc + kq * 8;
            int grow = row0 + r;
            const unsigned short* src;
            if (AMODE == 0) {
                src = A + (size_t)grow * K1 + gk;
            } else if (AMODE == 1) {
                int e = (grow < nrows) ? grow : 0;
                if (gk < H)          src = Xb + (size_t)snd[e] * H + gk;
                else if (gk < 2 * H) src = Xb + (size_t)rcv[e] * H + (gk - H);
                else                 src = Eb + (size_t)grow * H + (gk - 2 * H);
            } else {
                if (gk < H) src = Xb + (size_t)grow * H + gk;
                else        src = Gb + (size_t)grow * H + (gk - H);
            }
            uint4 v = *reinterpret_cast<const uint4*>(src);
            *reinterpret_cast<uint4*>(&As[r * SA + kq * 8]) = v;
        }
        constexpr int LPT_B = H * KQ / 256;
#pragma unroll
        for (int it = 0; it < LPT_B; ++it) {
            int q = tid + it * 256;
            int c = q / KQ;
            int kq = q % KQ;
            uint4 v = *reinterpret_cast<const uint4*>(Bt1 + (size_t)c * K1 + kc + kq * 8);
            *reinterpret_cast<uint4*>(&Bs[c * SB + kq * 8]) = v;
        }
        __syncthreads();
#pragma unroll
        for (int ks = 0; ks < BK1 / 32; ++ks) {
            short8 af[WR];
#pragma unroll
            for (int i = 0; i < WR; ++i)
                af[i] = *reinterpret_cast<const short8*>(
                    &As[(wrow + i * 16 + l15) * SA + ks * 32 + lhi * 8]);
#pragma unroll
            for (int j = 0; j < 8; ++j) {
                short8 bfr = *reinterpret_cast<const short8*>(
                    &Bs[(j * 16 + l15) * SB + ks * 32 + lhi * 8]);
#pragma unroll
                for (int i = 0; i < WR; ++i)
                    acc[i][j] = __builtin_amdgcn_mfma_f32_16x16x32_bf16(af[i], bfr, acc[i][j], 0, 0, 0);
            }
        }
        __syncthreads();
    }

    // ---- h = relu(acc + b1) -> Hs (each wave writes only its own rows) ----
    {
        float b1v[8];
#pragma unroll
        for (int j = 0; j < 8; ++j) b1v[j] = bias1[j * 16 + l15];
#pragma unroll
        for (int i = 0; i < WR; ++i)
#pragma unroll
            for (int r = 0; r < 4; ++r) {
                int rl = wrow + i * 16 + lhi * 4 + r;
#pragma unroll
                for (int j = 0; j < 8; ++j) {
                    float v = acc[i][j][r] + b1v[j];
                    Hs[rl * SH + j * 16 + l15] = f2bf(v > 0.f ? v : 0.f);
                }
            }
    }

    // reset accumulators for stage 2
#pragma unroll
    for (int i = 0; i < WR; i++)
#pragma unroll
        for (int j = 0; j < 8; j++) acc[i][j] = (f32x4){0.f, 0.f, 0.f, 0.f};

    // ---- stage 2: K=128 over Hs ----
    for (int kc = 0; kc < H; kc += 64) {
        __syncthreads();  // protect Bs from previous use; also orders Hs writes
        // load B chunk: H(128) cols x 64 k = 1024 uint4 -> 4 iterations of 256 thr
#pragma unroll
        for (int it = 0; it < 4; ++it) {
            int q = tid + it * 256;
            int c = q >> 3;     // 0..127
            int kq = q & 7;     // 0..7
            uint4 v = *reinterpret_cast<const uint4*>(Bt2 + (size_t)c * H + kc + kq * 8);
            *reinterpret_cast<uint4*>(&Bs[c * SB + kq * 8]) = v;
        }
        __syncthreads();
#pragma unroll
        for (int ks = 0; ks < 2; ++ks) {
            short8 af[WR];
#pragma unroll
            for (int i = 0; i < WR; ++i)
                af[i] = *reinterpret_cast<const short8*>(
                    &Hs[(wrow + i * 16 + l15) * SH + kc + ks * 32 + lhi * 8]);
#pragma unroll
            for (int j = 0; j < 8; ++j) {
                short8 bfr = *reinterpret_cast<const short8*>(
                    &Bs[(j * 16 + l15) * SB + ks * 32 + lhi * 8]);
#pragma unroll
                for (int i = 0; i < WR; ++i)
                    acc[i][j] = __builtin_amdgcn_mfma_f32_16x16x32_bf16(af[i], bfr, acc[i][j], 0, 0, 0);
            }
        }
    }

    // ---- epilogue: bias2 + LN (+residual variants) ----
    float bv[8], gv[8], lv[8];
#pragma unroll
    for (int j = 0; j < 8; ++j) {
        bv[j] = bias2[j * 16 + l15];
        gv[j] = lng[j * 16 + l15];
        lv[j] = lnb[j * 16 + l15];
    }

#pragma unroll
    for (int i = 0; i < WR; ++i) {
#pragma unroll
        for (int r = 0; r < 4; ++r) {
            int row = row0 + wrow + i * 16 + lhi * 4 + r;
            float v[8];
            float s = 0.f, s2 = 0.f;
#pragma unroll
            for (int j = 0; j < 8; ++j) {
                v[j] = acc[i][j][r] + bv[j];
                s += v[j];
                s2 += v[j] * v[j];
            }
#pragma unroll
            for (int m = 1; m < 16; m <<= 1) {
                s += __shfl_xor(s, m);
                s2 += __shfl_xor(s2, m);
            }
            float mean = s * (1.f / 128.f);
            float var = s2 * (1.f / 128.f) - mean * mean;
            float rstd = rsqrtf(var + LN_EPS);
            if (row < nrows) {
#pragma unroll
                for (int j = 0; j < 8; ++j) {
                    float o = (v[j] - mean) * rstd * gv[j] + lv[j];
                    size_t off = (size_t)row * H + j * 16 + l15;
                    if (EPI == 1) {
                        out_fp[off] = o;
                        out_bf[off] = f2bf(o);
                    } else if (EPI == 2) {
                        float nx = out_fp[off] + o;
                        out_fp[off] = nx;
                        out_bf[off] = f2bf(nx);
                    } else {
                        float ne = out_fp[off] + o;
                        out_fp[off] = ne;
                        out_bf[off] = f2bf(ne);
                        enew_bf[off] = f2bf(o);
                    }
                }
            }
        }
    }
}

// ---------------- decoder (fp32, matches round-2 numerics) ----------------
__global__ void decoder_kernel(const float* __restrict__ x,
                               const float* __restrict__ frames,
                               const float* __restrict__ W1, const float* __restrict__ b1,
                               const float* __restrict__ W2, const float* __restrict__ b2,
                               const float* __restrict__ omean, const float* __restrict__ ostd,
                               float* __restrict__ outp) {
    __shared__ float xr[H];
    __shared__ float hr[H];
    __shared__ float red[2][2];
    int n = blockIdx.x;
    int t = threadIdx.x;  // 128 threads
    xr[t] = x[n * H + t];
    __syncthreads();
    float acc = 0.f;
#pragma unroll 8
    for (int k = 0; k < H; k++) acc += xr[k] * W1[k * H + t];
    hr[t] = fmaxf(acc + b1[t], 0.f);
    __syncthreads();
    float p0 = hr[t] * W2[t * 2 + 0];
    float p1 = hr[t] * W2[t * 2 + 1];
#pragma unroll
    for (int m = 1; m < 64; m <<= 1) {
        p0 += __shfl_xor(p0, m);
        p1 += __shfl_xor(p1, m);
    }
    if ((t & 63) == 0) { red[t >> 6][0] = p0; red[t >> 6][1] = p1; }
    __syncthreads();
    if (t < 2) {
        float d = red[0][t] + red[1][t] + b2[t];
        outp[n * 2 + t] = frames[n * 2 + t] + d * ostd[t] + omean[t];
    }
}

// ---------------- launch ----------------
extern "C" void kernel_launch(void* const* d_in, const int* in_sizes, int n_in,
                              void* d_out, int out_size, void* d_ws, size_t ws_size,
                              hipStream_t stream) {
    (void)in_sizes; (void)n_in; (void)out_size; (void)ws_size;
    const int*   node_type  = (const int*)  d_in[0];
    const int*   edge_index = (const int*)  d_in[1];
    const float* frames     = (const float*)d_in[2];
    const float* edge_feats = (const float*)d_in[3];
    const float* nmean      = (const float*)d_in[4];
    const float* nstd       = (const float*)d_in[5];
    const float* omean      = (const float*)d_in[6];
    const float* ostd       = (const float*)d_in[7];
    const float* enc_nW1    = (const float*)d_in[8];
    const float* enc_nb1    = (const float*)d_in[9];
    const float* enc_nW2    = (const float*)d_in[10];
    const float* enc_nb2    = (const float*)d_in[11];
    const float* enc_nlng   = (const float*)d_in[12];
    const float* enc_nlnb   = (const float*)d_in[13];
    const float* enc_eW1    = (const float*)d_in[14];
    const float* enc_eb1    = (const float*)d_in[15];
    const float* enc_eW2    = (const float*)d_in[16];
    const float* enc_eb2    = (const float*)d_in[17];
    const float* enc_elng   = (const float*)d_in[18];
    const float* enc_elnb   = (const float*)d_in[19];
    const float* eb_W1      = (const float*)d_in[20];
    const float* eb_b1      = (const float*)d_in[21];
    const float* eb_W2      = (const float*)d_in[22];
    const float* eb_b2      = (const float*)d_in[23];
    const float* eb_g       = (const float*)d_in[24];
    const float* eb_bn      = (const float*)d_in[25];
    const float* nb_W1      = (const float*)d_in[26];
    const float* nb_b1      = (const float*)d_in[27];
    const float* nb_W2      = (const float*)d_in[28];
    const float* nb_b2      = (const float*)d_in[29];
    const float* nb_g       = (const float*)d_in[30];
    const float* nb_bn      = (const float*)d_in[31];
    const float* dec_W1     = (const float*)d_in[32];
    const float* dec_b1     = (const float*)d_in[33];
    const float* dec_W2     = (const float*)d_in[34];
    const float* dec_b2     = (const float*)d_in[35];

    const int* snd = edge_index;
    const int* rcv = edge_index + N_EDGES;

    // ---- workspace layout ----
    char* p = (char*)d_ws;
    auto alloc = [&](size_t bytes) {
        void* r = (void*)p;
        p += (bytes + 255) & ~(size_t)255;
        return r;
    };
    float* x_fp  = (float*)alloc((size_t)NPAD * H * 4);
    float* e_fp  = (float*)alloc((size_t)EPAD * H * 4);
    unsigned short* x_bf   = (unsigned short*)alloc((size_t)NPAD * H * 2);
    unsigned short* e_bf   = (unsigned short*)alloc((size_t)EPAD * H * 2);
    unsigned short* enew   = (unsigned short*)alloc((size_t)EPAD * H * 2);
    unsigned short* agg_bf = (unsigned short*)alloc((size_t)NPAD * H * 2);
    unsigned short* a16b   = (unsigned short*)alloc((size_t)NPAD * 32 * 2);
    unsigned short* a4b    = (unsigned short*)alloc((size_t)EPAD * 32 * 2);
    unsigned short* wt_en1 = (unsigned short*)alloc((size_t)128 * 32 * 2);
    unsigned short* wt_ee1 = (unsigned short*)alloc((size_t)128 * 32 * 2);
    unsigned short* wt_en2 = (unsigned short*)alloc((size_t)128 * 128 * 2);
    unsigned short* wt_ee2 = (unsigned short*)alloc((size_t)128 * 128 * 2);
    unsigned short* wt_eb1 = (unsigned short*)alloc((size_t)NLAYERS * 128 * 384 * 2);
    unsigned short* wt_eb2 = (unsigned short*)alloc((size_t)NLAYERS * 128 * 128 * 2);
    unsigned short* wt_nb1 = (unsigned short*)alloc((size_t)NLAYERS * 128 * 256 * 2);
    unsigned short* wt_nb2 = (unsigned short*)alloc((size_t)NLAYERS * 128 * 128 * 2);
    int* counts  = (int*)alloc((size_t)N_NODES * 4);
    int* starts  = (int*)alloc((size_t)N_NODES * 4);
    int* cursor  = (int*)alloc((size_t)N_NODES * 4);
    int* esorted = (int*)alloc((size_t)N_EDGES * 4);

    // ---- prep ----
    prep_node<<<(NPAD * 32 + 255) / 256, 256, 0, stream>>>(node_type, frames, nmean, nstd, a16b);
    prep_edge<<<(EPAD * 32 + 255) / 256, 256, 0, stream>>>(edge_feats, a4b);
    auto tw = [&](const float* w, unsigned short* wt, int Kr, int Kp, int nmat) {
        int blocks = nmat * (Kp / 32) * 4;
        transpose_w_tiled<<<blocks, 256, 0, stream>>>(w, wt, Kr, Kp, nmat);
    };
    tw(enc_nW1, wt_en1, 11, 32, 1);
    tw(enc_eW1, wt_ee1, 3, 32, 1);
    tw(enc_nW2, wt_en2, 128, 128, 1);
    tw(enc_eW2, wt_ee2, 128, 128, 1);
    tw(eb_W1, wt_eb1, 384, 384, NLAYERS);
    tw(eb_W2, wt_eb2, 128, 128, NLAYERS);
    tw(nb_W1, wt_nb1, 256, 256, NLAYERS);
    tw(nb_W2, wt_nb2, 128, 128, NLAYERS);

    // ---- CSR ----
    hipMemsetAsync(counts, 0, (size_t)N_NODES * 4, stream);
    hipMemsetAsync(cursor, 0, (size_t)N_NODES * 4, stream);
    hist_kernel<<<(N_EDGES + 255) / 256, 256, 0, stream>>>(rcv, counts);
    scan_kernel<<<1, 1024, 0, stream>>>(counts, starts);
    scatter_kernel<<<(N_EDGES + 255) / 256, 256, 0, stream>>>(rcv, starts, cursor, esorted);

    const int gE = EPAD / 128;  // 547 (WR=2)
    const int gN = NPAD / 64;   // 158 (WR=1)
    const unsigned short* nu_ = nullptr;
    const int* ni_ = nullptr;
    unsigned short* nm_ = nullptr;

    // ---- encoders (fused MLP1+MLP2+LN) ----
    mlp_fused<32, 0, 1, 1><<<gN, 256, 0, stream>>>(a16b, nu_, nu_, nu_, ni_, ni_,
        wt_en1, enc_nb1, wt_en2, enc_nb2, enc_nlng, enc_nlnb,
        x_bf, x_fp, nm_, N_NODES);
    mlp_fused<32, 0, 1, 2><<<gE, 256, 0, stream>>>(a4b, nu_, nu_, nu_, ni_, ni_,
        wt_ee1, enc_eb1, wt_ee2, enc_eb2, enc_elng, enc_elnb,
        e_bf, e_fp, nm_, N_EDGES);

    // ---- processor ----
    for (int l = 0; l < NLAYERS; ++l) {
        mlp_fused<384, 1, 3, 2><<<gE, 256, 0, stream>>>(nu_, x_bf, e_bf, nu_, snd, rcv,
            wt_eb1 + (size_t)l * 128 * 384, eb_b1 + l * H,
            wt_eb2 + (size_t)l * 128 * 128, eb_b2 + l * H, eb_g + l * H, eb_bn + l * H,
            e_bf, e_fp, enew, N_EDGES);
        agg_kernel<<<(N_NODES + 7) / 8, 256, 0, stream>>>(enew, esorted, starts, counts, agg_bf);
        mlp_fused<256, 2, 2, 1><<<gN, 256, 0, stream>>>(nu_, x_bf, nu_, agg_bf, ni_, ni_,
            wt_nb1 + (size_t)l * 128 * 256, nb_b1 + l * H,
            wt_nb2 + (size_t)l * 128 * 128, nb_b2 + l * H, nb_g + l * H, nb_bn + l * H,
            x_bf, x_fp, nm_, N_NODES);
    }

    // ---- decoder (fp32) ----
    decoder_kernel<<<N_NODES, 128, 0, stream>>>(x_fp, frames, dec_W1, dec_b1, dec_W2, dec_b2,
                                                omean, ostd, (float*)d_out);
}